// Round 11
// baseline (692.042 us; speedup 1.0000x reference)
//
#include <hip/hip_runtime.h>
#include <hip/hip_fp16.h>
#include <math.h>

#define TOK 2048      // B*S
#define HD 2048       // hidden
#define VOC 32000
#define BM 256
#define BN 256
#define BK 64
#define NT (HD/BK)                // 32 K-tiles
#define NCH (VOC/64)              // 500 col-chunks of 64
#define NBLK ((TOK/BM)*(VOC/BN))  // 8*125 = 1000

typedef _Float16 half8 __attribute__((ext_vector_type(8)));
typedef float float4v __attribute__((ext_vector_type(4)));

#define GLB __attribute__((address_space(1)))
#define LDSAS __attribute__((address_space(3)))

static __device__ __forceinline__ void gload_lds16(const void* g, void* l) {
  __builtin_amdgcn_global_load_lds((const GLB unsigned int*)g,
                                   (LDSAS unsigned int*)l, 16, 0, 0);
}

static __device__ __forceinline__ float4v mfma16(half8 a, half8 b, float4v c) {
  return __builtin_amdgcn_mfma_f32_16x16x32_f16(a, b, c, 0, 0, 0);
}

// ---------- fp32 -> f16 convert (memory-bound, vectorized) ----------
__global__ void cvt_f32_f16(const float* __restrict__ in,
                            _Float16* __restrict__ out, int n8) {
  for (int i = blockIdx.x * blockDim.x + threadIdx.x; i < n8;
       i += gridDim.x * blockDim.x) {
    float4v a = *(const float4v*)(in + (size_t)i*8);
    float4v b = *(const float4v*)(in + (size_t)i*8 + 4);
    half8 h;
    #pragma unroll
    for (int j=0;j<4;j++) { h[j] = (_Float16)a[j]; h[4+j] = (_Float16)b[j]; }
    *(half8*)(out + (size_t)i*8) = h;
  }
}

// m201-style 8-phase schedule on the R6 conflict-free layout.
// Units (16KB): u0=A kk0 @CB, u1=B kk0 @CB+16K, u2=A kk1 @CB+32K, u3=B kk1
// @CB+48K; CB alternates {0,65536}. Per K-tile t, 4 phases, each:
//   {ds_read own subtile; 2 gload_lds; barrier; lgkmcnt(0)+sched_barrier(0);
//    setprio(1); 16 MFMA; setprio(0); barrier}
// Staging: P0 -> (t+1)u2, P1 -> (t+1)u3, P2 -> (t+2)u0, P3 -> (t+2)u1.
// vmcnt(4) at end of P3 only (4 newest in flight; tile t+1 fully landed).
// WAR hazards: each stage target's last reader finished >=1 barrier before
// the stage issue (verified R4; layout change does not alter region mapping).
template<int CB, bool SG01, bool SG23, int VMN>
__device__ __forceinline__ void ktile(
    unsigned char* ldsby, const char* Xb, const char* Wb,
    int sA0, int sA1, int sB0, int sB1,
    int ldst0, int ldst1, int kbn,
    const int (&aofs)[8], const int (&bofs)[4], float4v (&acc)[8][4])
{
  half8 af[4], bf[4];

  // ---------------- P0: m0-3 x kk0 ----------------
  #pragma unroll
  for (int m=0;m<4;m++) af[m] = *(const half8*)(ldsby + CB + aofs[m]);
  #pragma unroll
  for (int n=0;n<4;n++) bf[n] = *(const half8*)(ldsby + CB + 16384 + bofs[n]);
  if (SG01) {   // stage (t+1) u2 = A kk1 -> other buf
    gload_lds16(Xb + (sA0 + kbn + 64), ldsby + ((CB^65536) + 32768) + ldst0);
    gload_lds16(Xb + (sA1 + kbn + 64), ldsby + ((CB^65536) + 32768) + ldst1);
  }
  __builtin_amdgcn_s_barrier();
  asm volatile("s_waitcnt lgkmcnt(0)" ::: "memory");
  __builtin_amdgcn_sched_barrier(0);
  __builtin_amdgcn_s_setprio(1);
  #pragma unroll
  for (int m=0;m<4;m++)
    #pragma unroll
    for (int n=0;n<4;n++)
      acc[m][n] = mfma16(af[m], bf[n], acc[m][n]);
  __builtin_amdgcn_s_setprio(0);
  __builtin_amdgcn_s_barrier();

  // ---------------- P1: m4-7 x kk0 (bf reused) ----------------
  #pragma unroll
  for (int m=0;m<4;m++) af[m] = *(const half8*)(ldsby + CB + aofs[4+m]);
  if (SG01) {   // stage (t+1) u3 = B kk1 -> other buf
    gload_lds16(Wb + (sB0 + kbn + 64), ldsby + ((CB^65536) + 49152) + ldst0);
    gload_lds16(Wb + (sB1 + kbn + 64), ldsby + ((CB^65536) + 49152) + ldst1);
  }
  __builtin_amdgcn_s_barrier();
  asm volatile("s_waitcnt lgkmcnt(0)" ::: "memory");
  __builtin_amdgcn_sched_barrier(0);
  __builtin_amdgcn_s_setprio(1);
  #pragma unroll
  for (int m=0;m<4;m++)
    #pragma unroll
    for (int n=0;n<4;n++)
      acc[4+m][n] = mfma16(af[m], bf[n], acc[4+m][n]);
  __builtin_amdgcn_s_setprio(0);
  __builtin_amdgcn_s_barrier();

  // ---------------- P2: m0-3 x kk1 ----------------
  #pragma unroll
  for (int m=0;m<4;m++) af[m] = *(const half8*)(ldsby + CB + 32768 + aofs[m]);
  #pragma unroll
  for (int n=0;n<4;n++) bf[n] = *(const half8*)(ldsby + CB + 49152 + bofs[n]);
  if (SG23) {   // stage (t+2) u0 = A kk0 -> current buf
    gload_lds16(Xb + (sA0 + kbn + 128), ldsby + CB + ldst0);
    gload_lds16(Xb + (sA1 + kbn + 128), ldsby + CB + ldst1);
  }
  __builtin_amdgcn_s_barrier();
  asm volatile("s_waitcnt lgkmcnt(0)" ::: "memory");
  __builtin_amdgcn_sched_barrier(0);
  __builtin_amdgcn_s_setprio(1);
  #pragma unroll
  for (int m=0;m<4;m++)
    #pragma unroll
    for (int n=0;n<4;n++)
      acc[m][n] = mfma16(af[m], bf[n], acc[m][n]);
  __builtin_amdgcn_s_setprio(0);
  __builtin_amdgcn_s_barrier();

  // ---------------- P3: m4-7 x kk1 (bf reused) ----------------
  #pragma unroll
  for (int m=0;m<4;m++) af[m] = *(const half8*)(ldsby + CB + 32768 + aofs[4+m]);
  if (SG23) {   // stage (t+2) u1 = B kk0 -> current buf
    gload_lds16(Wb + (sB0 + kbn + 128), ldsby + (CB + 16384) + ldst0);
    gload_lds16(Wb + (sB1 + kbn + 128), ldsby + (CB + 16384) + ldst1);
  }
  __builtin_amdgcn_s_barrier();
  asm volatile("s_waitcnt lgkmcnt(0)" ::: "memory");
  __builtin_amdgcn_sched_barrier(0);
  __builtin_amdgcn_s_setprio(1);
  #pragma unroll
  for (int m=0;m<4;m++)
    #pragma unroll
    for (int n=0;n<4;n++)
      acc[4+m][n] = mfma16(af[m], bf[n], acc[4+m][n]);
  __builtin_amdgcn_s_setprio(0);
  if (VMN == 4)      asm volatile("s_waitcnt vmcnt(4)" ::: "memory");
  else if (VMN == 0) asm volatile("s_waitcnt vmcnt(0)" ::: "memory");
  __builtin_amdgcn_s_barrier();
}

// ---------- 256x256 8-phase GEMM with fused row stats ----------
__global__ __launch_bounds__(512, 2) void gemm_stats_f16(
    const _Float16* __restrict__ Xh, const _Float16* __restrict__ Wh,
    const float* __restrict__ bias,
    float* __restrict__ pmax, float* __restrict__ psum,
    float* __restrict__ bsum, int computeSum)
{
  __shared__ unsigned char ldsbuf[131072];
  unsigned char* ldsby = ldsbuf;

  int bid = blockIdx.x;
  int swz = (bid & 7) * (NBLK/8) + (bid >> 3);   // XCD-aware, bijective (1000%8==0)
  int rowt = swz & 7;          // fast axis: 8 row tiles share W panel in XCD L2
  int colt = swz >> 3;         // 125 col tiles
  int brow = rowt * BM;
  int bcol = colt * BN;

  int tid  = threadIdx.x;
  int lane = tid & 63;
  int wv   = tid >> 6;
  int wr   = wv >> 2;          // 0..1 (M)
  int wc   = wv & 3;           // 0..3 (N)
  int l15  = lane & 15;
  int q    = lane >> 4;

  // fragment offsets within a 16KB unit (R6 pair-interleave, 0 conflicts)
  int aswz = (((((l15 & 1) << 2) | q) ^ ((l15 >> 1) & 7)) << 4) + ((l15 >> 1) << 7);
  int aofs[8], bofs[4];
  #pragma unroll
  for (int m = 0; m < 8; m++) aofs[m] = wr*8192 + m*1024 + aswz;
  #pragma unroll
  for (int n = 0; n < 4; n++) bofs[n] = wc*4096 + n*1024 + aswz;

  // staging: linear LDS dest, inverse-permuted global source (R6-verified)
  int s8  = (tid & 7) ^ ((tid >> 3) & 7);
  int rl  = wv*16 + (((tid >> 3) & 7) << 1) + (s8 >> 2);
  int kc  = (s8 & 3) << 4;
  int sA0 = (brow + rl)*(HD*2) + kc;
  int sA1 = sA0 + 128*(HD*2);
  int sB0 = (bcol + rl)*(HD*2) + kc;
  int sB1 = sB0 + 128*(HD*2);
  int ldst0 = (wv << 10);          // wave-uniform LDS dest (+lane*16 by HW)
  int ldst1 = (wv << 10) + 8192;

  const char* Xb = (const char*)Xh;
  const char* Wb = (const char*)Wh;

  float4v acc[8][4];
  #pragma unroll
  for (int m=0;m<8;m++)
    #pragma unroll
    for (int n=0;n<4;n++) acc[m][n] = (float4v){0.f,0.f,0.f,0.f};

  // prologue: tile0 u0..u3 + tile1 u0,u1 (12 loads); vmcnt(4) -> tile0 landed
  gload_lds16(Xb + sA0,       ldsby + 0     + ldst0);
  gload_lds16(Xb + sA1,       ldsby + 0     + ldst1);
  gload_lds16(Wb + sB0,       ldsby + 16384 + ldst0);
  gload_lds16(Wb + sB1,       ldsby + 16384 + ldst1);
  gload_lds16(Xb + (sA0+64),  ldsby + 32768 + ldst0);
  gload_lds16(Xb + (sA1+64),  ldsby + 32768 + ldst1);
  gload_lds16(Wb + (sB0+64),  ldsby + 49152 + ldst0);
  gload_lds16(Wb + (sB1+64),  ldsby + 49152 + ldst1);
  gload_lds16(Xb + (sA0+128), ldsby + 65536 + ldst0);
  gload_lds16(Xb + (sA1+128), ldsby + 65536 + ldst1);
  gload_lds16(Wb + (sB0+128), ldsby + 81920 + ldst0);
  gload_lds16(Wb + (sB1+128), ldsby + 81920 + ldst1);
  asm volatile("s_waitcnt vmcnt(4)" ::: "memory");
  __builtin_amdgcn_s_barrier();

  int kbn = 128;   // byte k-offset of tile t+1
  #pragma unroll 1
  for (int i = 0; i < 15; ++i) {
    ktile<0,     true, true, 4>(ldsby, Xb, Wb, sA0,sA1,sB0,sB1, ldst0,ldst1, kbn, aofs, bofs, acc);
    kbn += 128;
    ktile<65536, true, true, 4>(ldsby, Xb, Wb, sA0,sA1,sB0,sB1, ldst0,ldst1, kbn, aofs, bofs, acc);
    kbn += 128;
  }
  // t=30: stage tile31 kk1 only; drain so tile31 is fully resident
  ktile<0,     true,  false, 0>(ldsby, Xb, Wb, sA0,sA1,sB0,sB1, ldst0,ldst1, kbn, aofs, bofs, acc);
  kbn += 128;
  // t=31: no staging
  ktile<65536, false, false, -1>(ldsby, Xb, Wb, sA0,sA1,sB0,sB1, ldst0,ldst1, kbn, aofs, bofs, acc);

  // ---------------- epilogue: bias + per-row max/sumexp ----------------
  float bv[4];
  #pragma unroll
  for (int n=0;n<4;n++) bv[n] = bias[bcol + wc*64 + n*16 + l15];

  float lsum = 0.f;
  int ch = colt*4 + wc;
  #pragma unroll
  for (int m=0;m<8;m++) {
    #pragma unroll
    for (int r=0;r<4;r++) {
      float v0 = acc[m][0][r] + bv[0];
      float v1 = acc[m][1][r] + bv[1];
      float v2 = acc[m][2][r] + bv[2];
      float v3 = acc[m][3][r] + bv[3];
      if (computeSum) lsum += v0+v1+v2+v3;
      float mx = fmaxf(fmaxf(v0,v1), fmaxf(v2,v3));
      #pragma unroll
      for (int off=1; off<16; off<<=1) mx = fmaxf(mx, __shfl_xor(mx, off, 64));
      float se = __expf(v0-mx)+__expf(v1-mx)+__expf(v2-mx)+__expf(v3-mx);
      #pragma unroll
      for (int off=1; off<16; off<<=1) se += __shfl_xor(se, off, 64);
      if (l15 == 0) {
        int row = brow + wr*128 + m*16 + (lane>>4)*4 + r;
        pmax[(size_t)row*NCH + ch] = mx;
        psum[(size_t)row*NCH + ch] = se;
      }
    }
  }

  if (computeSum) {
    #pragma unroll
    for (int off=1; off<64; off<<=1) lsum += __shfl_xor(lsum, off, 64);
    __syncthreads();
    float* red = (float*)ldsbuf;
    if (lane == 0) red[wv] = lsum;
    __syncthreads();
    if (tid == 0) {
      float s = 0.f;
      for (int w=0; w<8; w++) s += red[w];
      bsum[blockIdx.x] = s;
    }
  }
}

// ---------- per-row combine ----------
__global__ void row_combine(const float* __restrict__ pmax,
                            const float* __restrict__ psum,
                            const float* __restrict__ mask,
                            float* __restrict__ tok)
{
  int row = blockIdx.x;
  int lane = threadIdx.x;
  float M = -INFINITY;
  for (int c = lane; c < NCH; c += 64) M = fmaxf(M, pmax[(size_t)row*NCH + c]);
  #pragma unroll
  for (int off=1; off<64; off<<=1) M = fmaxf(M, __shfl_xor(M, off, 64));
  float L = 0.f;
  for (int c = lane; c < NCH; c += 64)
    L += psum[(size_t)row*NCH + c] * __expf(pmax[(size_t)row*NCH + c] - M);
  #pragma unroll
  for (int off=1; off<64; off<<=1) L += __shfl_xor(L, off, 64);
  if (lane == 0) tok[row] = -logf(L) * mask[row];
}

// ---------- finalize ----------
__global__ void finalize(const float* __restrict__ tokP,
                         const float* __restrict__ tokR,
                         const float* __restrict__ rewards,
                         const float* __restrict__ bsum, int nbsum,
                         float* __restrict__ out)
{
  __shared__ float red[256];
  __shared__ float seqP[4], seqR[4];
  int t = threadIdx.x;
  for (int b=0; b<4; b++) {
    float v = tokP[b*512 + t] + tokP[b*512 + 256 + t];
    red[t] = v; __syncthreads();
    for (int s=128; s>0; s>>=1) { if (t < s) red[t] += red[t+s]; __syncthreads(); }
    if (t == 0) seqP[b] = red[0];
    __syncthreads();
    v = tokR[b*512 + t] + tokR[b*512 + 256 + t];
    red[t] = v; __syncthreads();
    for (int s=128; s>0; s>>=1) { if (t < s) red[t] += red[t+s]; __syncthreads(); }
    if (t == 0) seqR[b] = red[0];
    __syncthreads();
  }
  float ls = 0.f;
  for (int i=t; i<nbsum; i+=256) ls += bsum[i];
  red[t] = ls; __syncthreads();
  for (int s=128; s>0; s>>=1) { if (t < s) red[t] += red[t+s]; __syncthreads(); }
  if (t == 0) {
    float r0=rewards[0], r1=rewards[1], r2=rewards[2], r3=rewards[3];
    float rm = (r0+r1+r2+r3)*0.25f;
    float var = ((r0-rm)*(r0-rm)+(r1-rm)*(r1-rm)+(r2-rm)*(r2-rm)+(r3-rm)*(r3-rm))/3.f;
    float rstd = sqrtf(var);
    float adv[4] = {r0-rm, r1-rm, r2-rm, r3-rm};
    if (rstd > 0.f) { for (int b=0;b<4;b++) adv[b] /= rstd; }
    float loss=0.f, sm=0.f, km=0.f;
    for (int b=0;b<4;b++) {
      float kl = seqP[b] - seqR[b];
      loss += -(adv[b]*seqP[b]) + 0.1f*kl;
      sm += seqP[b]; km += kl;
    }
    loss *= 0.25f; sm *= 0.25f; km *= 0.25f;
    float sv = 0.f;
    for (int b=0;b<4;b++) { float d = seqP[b]-sm; sv += d*d; }
    float sstd = sqrtf(sv/3.f);
    out[0] = loss;
    out[1] = sm;
    out[2] = sstd;
    out[3] = red[0] / ((float)TOK * (float)VOC);
    out[4] = km;
  }
}

extern "C" void kernel_launch(void* const* d_in, const int* in_sizes, int n_in,
                              void* d_out, int out_size, void* d_ws, size_t ws_size,
                              hipStream_t stream) {
  const float* W    = (const float*)d_in[0];
  const float* X    = (const float*)d_in[1];
  const float* mask = (const float*)d_in[2];
  const float* rew  = (const float*)d_in[3];
  const float* bias = (const float*)d_in[4];
  const float* Xr   = (const float*)d_in[5];
  const float* Wr   = (const float*)d_in[6];
  const float* br   = (const float*)d_in[7];
  float* out = (float*)d_out;

  float* pmax = (float*)d_ws;                       // 2048*500
  float* psum = pmax + (size_t)TOK*NCH;             // 2048*500
  float* tokP = psum + (size_t)TOK*NCH;             // 2048
  float* tokR = tokP + TOK;                         // 2048
  float* bsum = tokR + TOK;                         // 4096 (pad)

  size_t headFloats = (size_t)TOK*NCH*2 + TOK*2 + 4096;
  size_t offXh = headFloats * 4;
  _Float16* Xh = (_Float16*)((unsigned char*)d_ws + offXh);
  _Float16* Wh = (_Float16*)((unsigned char*)d_ws + offXh + (size_t)TOK*HD*2);

  cvt_f32_f16<<<2048, 256, 0, stream>>>(X,  Xh, TOK*HD/8);
  cvt_f32_f16<<<2048, 256, 0, stream>>>(W,  Wh, VOC*HD/8);
  gemm_stats_f16<<<NBLK, 512, 0, stream>>>(Xh, Wh, bias, pmax, psum, bsum, 1);
  row_combine<<<TOK, 64, 0, stream>>>(pmax, psum, mask, tokP);
  cvt_f32_f16<<<2048, 256, 0, stream>>>(Xr, Xh, TOK*HD/8);
  cvt_f32_f16<<<2048, 256, 0, stream>>>(Wr, Wh, VOC*HD/8);
  gemm_stats_f16<<<NBLK, 512, 0, stream>>>(Xh, Wh, br, pmax, psum, bsum, 0);
  row_combine<<<TOK, 64, 0, stream>>>(pmax, psum, mask, tokR);
  finalize<<<1, 256, 0, stream>>>(tokP, tokR, rew, bsum, NBLK, out);
}